// Round 3
// baseline (309.382 us; speedup 1.0000x reference)
//
#include <hip/hip_runtime.h>

// VQ-VAE forward: x [64,64,32,32] f32 (NCHW, C==D), weight [512,64] f32.
// d_out: loss (1) | q_out (4194304, NCHW) | encodings (33554432, [N,K]).
//
// R13 = R12 with the DPP ctrl passed as a template (compile-time) constant
// (__builtin_amdgcn_update_dpp requires a literal ctrl). Design unchanged:
//  - codebook resident per-lane in VGPRs: lane owns codes c0=wv*128+lane,
//    c1=c0+64 (128 VGPR, loaded once; launch_bounds(256,2) = 256 budget)
//  - x rows stream via the SCALAR path (uniform address -> s_load); scalar
//    v_fma_f32 folds 1 SGPR source -> zero per-lane operand traffic, zero
//    LDS in the main loop
//  - per-row argmin: DPP v_min butterfly (scales 1..8) + shfl_xor 16/32,
//    then min-index among exact-equal dists == strict-< ascending-k scan
//  - one-hot: ZERO-PREFILL at kernel start (stores drain during compute;
//    row loop waits lgkm only), scatter 1.0s after the post-loop barrier
//    (syncthreads vmcnt(0) drain orders same-address stores)
// Dist/x2/e2/loss chains bit-identical to R11 (passing): fused-FMA E/O
// chains ascending dp, dot=accE+accO, dist=(x2+e2)-2*dot; x2 = mul-then-add
// ascending d (moved to prep, same chain).

#define NROWS 65536
#define DIM 64
#define KCODES 512
#define HW 1024
#define TPB 256
#define RPB 128                     // rows per block
#define NBLOCKS (NROWS / RPB)       // 512

// d_ws float offsets
#define E2_OFF 0                    // e2 [512]
#define X2_OFF 512                  // x2 [65536]
#define PART_OFF (512 + NROWS)      // partials [512]

typedef float v2f __attribute__((ext_vector_type(2)));
typedef float v4f __attribute__((ext_vector_type(4)));

template <int CTRL>
__device__ __forceinline__ float dppmin_f(float v) {
    const int o = __builtin_amdgcn_update_dpp(
        0, __float_as_int(v), CTRL, 0xF, 0xF, false);
    return fminf(v, __int_as_float(o));
}
template <int CTRL>
__device__ __forceinline__ int dppmin_i(int v) {
    const int o = __builtin_amdgcn_update_dpp(0, v, CTRL, 0xF, 0xF, false);
    return (o < v) ? o : v;          // indices >= 0: signed == unsigned
}

__global__ __launch_bounds__(256) void vq_prep(
    const float* __restrict__ x, const float* __restrict__ w,
    float* __restrict__ ws)
{
    const int bid = blockIdx.x;
    if (bid < 2) {
        // e2: ascending-d mul-then-add chain (same as R11)
        const int k = bid * 256 + threadIdx.x;
        float s = 0.0f;
        for (int d = 0; d < DIM; ++d) {
            const float v = w[k * DIM + d];
            s = __fadd_rn(s, __fmul_rn(v, v));
        }
        ws[E2_OFF + k] = s;
    } else {
        // x2 per row: ascending-d mul-then-add chain (identical to R11's
        // in-kernel chain: d = 2dp, 2dp+1 ascending == plain d ascending).
        // Consecutive threads -> consecutive hw -> coalesced per d.
        const int n  = (bid - 2) * 256 + threadIdx.x;
        const int b  = n >> 10;
        const int hw = n & 1023;
        const float* xb = x + (size_t)b * (DIM * HW) + hw;
        float s = 0.0f;
        #pragma unroll 8
        for (int d = 0; d < DIM; ++d) {
            const float v = xb[(size_t)d * HW];
            s = __fadd_rn(s, __fmul_rn(v, v));
        }
        ws[X2_OFF + n] = s;
    }
}

__global__ __launch_bounds__(TPB, 2) void vq_main(
    const float* __restrict__ x, const float* __restrict__ w,
    const float* __restrict__ ws, float* __restrict__ out,
    float* __restrict__ partial)
{
    __shared__ float swb[4][RPB];
    __shared__ int   swi[4][RPB];
    __shared__ int   idxf[RPB];
    __shared__ float lred[4];

    const int t    = threadIdx.x;
    const int lane = t & 63;
    const int wv   = __builtin_amdgcn_readfirstlane(t >> 6);
    const int n0   = blockIdx.x * RPB;
    const int b    = n0 >> 10;        // 1024 % 128 == 0: no b straddle
    const int hw0  = n0 & 1023;

    // ---- resident codebook: lane owns codes c0, c1 (wave covers 128,
    // chunk ranges ascend with wv -> cross-wave reduce is lexicographic)
    const int c0 = wv * 128 + lane;
    const int c1 = c0 + 64;
    v2f w0[32], w1[32];
    #pragma unroll
    for (int j = 0; j < 32; ++j)
        w0[j] = *(const v2f*)(w + (size_t)c0 * DIM + 2 * j);
    #pragma unroll
    for (int j = 0; j < 32; ++j)
        w1[j] = *(const v2f*)(w + (size_t)c1 * DIM + 2 * j);
    const float e20 = ws[E2_OFF + c0];
    const float e21 = ws[E2_OFF + c1];

    // ---- zero-prefill this block's encodings slab (idx-independent 89% of
    // HBM writes); stores drain in background under the whole row loop.
    // Issued AFTER the w/e2 loads so their waits don't drain the store queue.
    float* slab = out + 1 + (size_t)NROWS * DIM + (size_t)n0 * KCODES;
    if (t < 3) slab[t] = 0.0f;                       // float idx == 1 mod 4
    if (t == 4) slab[RPB * KCODES - 1] = 0.0f;
    {
        v4f* s4 = (v4f*)(slab + 3);                  // 16B-aligned
        const int nf4 = (RPB * KCODES - 4) / 4;      // 16383
        const v4f z = (v4f){0.0f, 0.0f, 0.0f, 0.0f};
        for (int f = t; f < nf4; f += TPB) s4[f] = z;
    }

    // ---- row loop: x row via SCALAR loads (uniform addr); main loop has
    // zero LDS traffic and zero vmcnt waits (prefill stores never block it).
    const float* xrb = x + (size_t)b * (DIM * HW) + hw0;
    const float* x2p = ws + X2_OFF + n0;
    #pragma unroll 1
    for (int r = 0; r < RPB; ++r) {
        float xs[DIM];
        #pragma unroll
        for (int d = 0; d < DIM; ++d)
            xs[d] = xrb[(size_t)d * HW + r];         // uniform -> s_load
        const float x2 = x2p[r];                     // uniform -> s_load

        // fused-FMA E/O chains, ascending dp == R11's pk_fma lanes
        float aE0 = 0.0f, aO0 = 0.0f, aE1 = 0.0f, aO1 = 0.0f;
        #pragma unroll
        for (int j = 0; j < 32; ++j) {
            aE0 = __builtin_fmaf(xs[2 * j],     w0[j][0], aE0);
            aO0 = __builtin_fmaf(xs[2 * j + 1], w0[j][1], aO0);
            aE1 = __builtin_fmaf(xs[2 * j],     w1[j][0], aE1);
            aO1 = __builtin_fmaf(xs[2 * j + 1], w1[j][1], aO1);
        }
        const float dot0 = aE0 + aO0;                // plain add, as R11
        const float dot1 = aE1 + aO1;
        const float d0 = __fsub_rn(__fadd_rn(x2, e20),
                                   __fmul_rn(2.0f, dot0));
        const float d1 = __fsub_rn(__fadd_rn(x2, e21),
                                   __fmul_rn(2.0f, dot1));

        // wave-min dist: DPP (1,2,4,8) + shfl (16,32); exact (min passes
        // values through unchanged; dists are finite, no NaN)
        float m = fminf(d0, d1);
        m = dppmin_f<0xB1>(m);                       // quad_perm xor1
        m = dppmin_f<0x4E>(m);                       // quad_perm xor2
        m = dppmin_f<0x141>(m);                      // row_half_mirror
        m = dppmin_f<0x140>(m);                      // row_mirror
        m = fminf(m, __shfl_xor(m, 16, 64));
        m = fminf(m, __shfl_xor(m, 32, 64));

        // lowest index among exact-equal minima (c0 < c1 checked first)
        // == strict-< ascending-k scan semantics
        int cand = (d0 == m) ? c0 : ((d1 == m) ? c1 : 0xFFFF);
        cand = dppmin_i<0xB1>(cand);
        cand = dppmin_i<0x4E>(cand);
        cand = dppmin_i<0x141>(cand);
        cand = dppmin_i<0x140>(cand);
        { const int o = __shfl_xor(cand, 16, 64); cand = (o < cand) ? o : cand; }
        { const int o = __shfl_xor(cand, 32, 64); cand = (o < cand) ? o : cand; }

        if (lane == 0) { swb[wv][r] = m; swi[wv][r] = cand; }
    }
    __syncthreads();   // also drains vmcnt(0): prefill zeros committed

    // ---- cross-wave argmin: chunk ranges ascend with wv -> lexicographic
    if (t < RPB) {
        float bb = swb[0][t]; int bi = swi[0][t];
        #pragma unroll
        for (int j = 1; j < 4; ++j) {
            const float ob = swb[j][t]; const int oi = swi[j][t];
            if (ob < bb || (ob == bb && oi < bi)) { bb = ob; bi = oi; }
        }
        idxf[t] = bi;
    }
    __syncthreads();

    // ---- one-hot scatter: ordered after prefill by the barrier's vmcnt(0)
    if (t < RPB)
        slab[(size_t)t * KCODES + idxf[t]] = 1.0f;

    // ---- q gather/store + loss (R10's proven 256-thread split:
    // row = t&127, d-half = t>>7); x re-read coalesced (L2-hot)
    const int rt = t & 127;
    const int dg = t >> 7;
    const int widx = idxf[rt];
    const float* wrow = w + (size_t)widx * DIM + dg * 32;
    const float* xg = x + (size_t)b * (DIM * HW) + (size_t)dg * 32 * HW
                      + hw0 + rt;
    float* q = out + 1;
    float lsum = 0.0f;
    #pragma unroll
    for (int jj = 0; jj < 16; ++jj) {
        const int dE = dg * 32 + 2 * jj;
        const v2f wp2 = *(const v2f*)(wrow + 2 * jj);
        const float xE = xg[(size_t)(2 * jj) * HW];
        const float xO = xg[(size_t)(2 * jj + 1) * HW];
        const float dfE = __fsub_rn(wp2[0], xE);      // d ascending: E,O
        lsum = __fadd_rn(lsum, __fmul_rn(dfE, dfE));
        const float dfO = __fsub_rn(wp2[1], xO);
        lsum = __fadd_rn(lsum, __fmul_rn(dfO, dfO));
        q[(size_t)(b * DIM + dE) * HW + hw0 + rt]     = wp2[0];
        q[(size_t)(b * DIM + dE + 1) * HW + hw0 + rt] = wp2[1];
    }
    #pragma unroll
    for (int off = 32; off; off >>= 1) lsum += __shfl_down(lsum, off, 64);
    if (lane == 0) lred[wv] = lsum;
    __syncthreads();
    if (t == 0)
        partial[blockIdx.x] = (lred[0] + lred[1]) + (lred[2] + lred[3]);
}

__global__ __launch_bounds__(256) void vq_final(
    const float* __restrict__ partial, float* __restrict__ out)
{
    __shared__ float s[256];
    const int t = threadIdx.x;
    s[t] = partial[t] + partial[t + 256];
    __syncthreads();
    for (int off = 128; off; off >>= 1) {
        if (t < off) s[t] += s[t + off];
        __syncthreads();
    }
    if (t == 0) {
        const float m = s[0] / 4194304.0f;            // mean over B*H*W*D
        out[0] = __fadd_rn(m, __fmul_rn(0.25f, m));   // z_q + 0.25*z_e
    }
}

extern "C" void kernel_launch(void* const* d_in, const int* in_sizes, int n_in,
                              void* d_out, int out_size, void* d_ws, size_t ws_size,
                              hipStream_t stream) {
    const float* x = (const float*)d_in[0];
    const float* w = (const float*)d_in[1];
    float* out     = (float*)d_out;
    float* ws      = (float*)d_ws;

    vq_prep<<<258, 256, 0, stream>>>(x, w, ws);
    vq_main<<<NBLOCKS, TPB, 0, stream>>>(x, w, ws, out, ws + PART_OFF);
    vq_final<<<1, 256, 0, stream>>>(ws + PART_OFF, out);
}

// Round 4
// 241.875 us; speedup vs baseline: 1.2791x; 1.2791x over previous
//
#include <hip/hip_runtime.h>

// VQ-VAE forward: x [64,64,32,32] f32 (NCHW, C==D), weight [512,64] f32.
// d_out: loss (1) | q_out (4194304, NCHW) | encodings (33554432, [N,K]).
//
// R14 = R10 (proven 89.6us) with the w operand moved from LDS to the
// vector-memory/L1 pipe + in-loop one-hot zero-prefill.
//  - R10 was LDS-bound: 8 ds_read_b128 per wave-dp on the per-CU LDS unit
//    (768 cyc/CU-round vs 320 VALU cyc/SIMD). w fragments are now read
//    directly from ws's wTp layout via 4x global_load_dwordx4 per dp:
//    identical 16 floats, identical fragment order -> dist chain and
//    tie-break bit-identical to R10. Per-chunk wTp slice = 32KB = L1 size;
//    x stays in LDS so L1 holds only w -> L1-hot.
//  - w double-buffer staging, prefetch regs, and both per-chunk barriers
//    are deleted; the chunk loop is barrier-free (waves drift -> VM latency
//    self-overlaps). LDS shrinks to the x tile (32KB).
//  - encodings (128MB = 85% of HBM writes) zero-prefilled from INSIDE the
//    dp loop (1 v4f store per 2 dp per thread -> store-queue depth ~2, so
//    w-load vmcnt waits sweep along <=2 stores; zeros drain under compute).
//    1.0 scatter after the post-argmin __syncthreads (its vmcnt(0) drain
//    orders prefill before scatter; same CU -> same L2 -> ordered).
// Dist arithmetic + tie order bit-identical to R6/R7/R9/R10 (passing).

#define NROWS 65536
#define DIM 64
#define KCODES 512
#define HW 1024
#define TPB 256
#define RPB 128                     // rows per block
#define NBLOCKS (NROWS / RPB)       // 512

// d_ws float offsets
#define WT_OFF 0                    // wTp [32 dpair][512 k][2] = 32768 floats
#define E2_OFF 32768                // e2 [512]
#define PART_OFF 98816              // partials [512]

// dynamic LDS float offsets
#define XW 8192                     // xs: 32 dp x 128 rows x (E,O)
#define DYN_BYTES (XW * 4)          // 32768 B

typedef float v2f __attribute__((ext_vector_type(2)));
typedef float v4f __attribute__((ext_vector_type(4)));

__global__ __launch_bounds__(256) void vq_prep(
    const float* __restrict__ w, float* __restrict__ ws)
{
    // w -> wTp[dpair][k][2] (E,O interleave) + e2 (ascending-d chain)
    const int k = blockIdx.x * 256 + threadIdx.x;
    float s = 0.0f;
    for (int d = 0; d < DIM; ++d) {
        const float v = w[k * DIM + d];
        ws[WT_OFF + (d >> 1) * (KCODES * 2) + k * 2 + (d & 1)] = v;
        s = __fadd_rn(s, __fmul_rn(v, v));
    }
    ws[E2_OFF + k] = s;
}

__global__ __launch_bounds__(TPB) void vq_main(
    const float* __restrict__ x, const float* __restrict__ w,
    const float* __restrict__ ws, float* __restrict__ out,
    float* __restrict__ partial)
{
    extern __shared__ __align__(16) float smem[];   // [0,XW) = xs only
    __shared__ int   idxf[RPB];
    __shared__ float x2l[RPB];
    __shared__ float lred[4];

    const int t    = threadIdx.x;
    const int lane = t & 63;
    const int wv   = __builtin_amdgcn_readfirstlane(t >> 6);
    const int rg   = lane >> 4;       // 0..3: rows wv*32 + rg*8 .. +7
    const int kg   = lane & 15;       // 16 groups x 8 codes per chunk
    const int n0   = blockIdx.x * RPB;
    const int b    = n0 >> 10;        // 1024 % 128 == 0: no b straddle
    const int hw0  = n0 & 1023;

    // ---- encodings slab pointers + edge peel (2 tiny stores, pre-loop)
    float* slab = out + 1 + (size_t)NROWS * DIM + (size_t)n0 * KCODES;
    v4f* s4 = (v4f*)(slab + 3);                   // 16B-aligned
    if (t < 3) slab[t] = 0.0f;                    // covered by scatter if hit
    if (t == 4) slab[RPB * KCODES - 1] = 0.0f;

    // ---- stage x tile (128 rows) into LDS, (E,O) interleaved, unpadded:
    // xs[dp*256 + (row>>3)*16 + (row&7)*2 (+1 for odd d)]
    #pragma unroll
    for (int i = 0; i < 4; ++i) {
        const int task = i * 256 + t;          // 1024 tasks
        const int dp   = task >> 5;
        const int row4 = (task & 31) * 4;
        const float* pe = x + (size_t)(b * DIM + 2 * dp) * HW + hw0 + row4;
        const v4f xe = *(const v4f*)pe;        // 4 rows, even depth
        const v4f xo = *(const v4f*)(pe + HW); // 4 rows, odd depth
        float* dst = smem + dp * 256 + (row4 >> 3) * 16 + (row4 & 7) * 2;
        *(v4f*)dst       = (v4f){xe.x, xo.x, xe.y, xo.y};
        *(v4f*)(dst + 4) = (v4f){xe.z, xo.z, xe.w, xo.w};
    }
    __syncthreads();   // xs visible

    // ---- x2 per row from LDS: same ascending-d mul-then-add chain as prep's
    if (t < RPB) {
        const float* xb = smem + (t >> 3) * 16 + (t & 7) * 2;
        float s = 0.0f;
        #pragma unroll 8
        for (int dp = 0; dp < 32; ++dp) {
            const v2f p = *(const v2f*)(xb + dp * 256);   // (E,O) of d=2dp
            s = __fadd_rn(s, __fmul_rn(p[0], p[0]));
            s = __fadd_rn(s, __fmul_rn(p[1], p[1]));
        }
        x2l[t] = s;
    }
    __syncthreads();   // x2l visible

    const float* e2p = ws + E2_OFF;
    const float* wTp = ws + WT_OFF;
    const int cj = wv * 4 + rg;                // x row-chunk id (0..15)
    const int rloc = wv * 32 + rg * 8;         // first row (block-local)
    const v4f x2a = *(const v4f*)(x2l + rloc);
    const v4f x2b = *(const v4f*)(x2l + rloc + 4);

    float best[8];
    int   bidx[8];
    #pragma unroll
    for (int r = 0; r < 8; ++r) { best[r] = 3.4e38f; bidx[r] = 0; }

    const v4f zf = (v4f){0.0f, 0.0f, 0.0f, 0.0f};

    // ---- 4 chunks of 128 codes, ascending (=> per-lane k ascending);
    // barrier-free: w frags from global wTp (L1-hot), x from LDS.
    #pragma unroll 1
    for (int c = 0; c < 4; ++c) {
        v2f acc[8][8];
        #pragma unroll
        for (int r = 0; r < 8; ++r)
            #pragma unroll
            for (int cc = 0; cc < 8; ++cc) acc[r][cc] = (v2f){0.f, 0.f};

        const float* xp = smem + cj * 16;
        const float* wp = wTp + c * 256 + kg * 16;   // + dp*1024 per iter
        const int fbase = t + (c << 4) * 256;        // prefill f = t+256*i
        #pragma unroll 4
        for (int dp = 0; dp < 32; ++dp) {
            const v4f X0 = *(const v4f*)(xp);        // rows 0,1 (E,O) pairs
            const v4f X1 = *(const v4f*)(xp + 4);    // rows 2,3
            const v4f X2 = *(const v4f*)(xp + 8);    // rows 4,5
            const v4f X3 = *(const v4f*)(xp + 12);   // rows 6,7
            const v4f W0 = *(const v4f*)(wp);        // codes 0,1 (E,O) pairs
            const v4f W1 = *(const v4f*)(wp + 4);    // codes 2,3
            const v4f W2 = *(const v4f*)(wp + 8);    // codes 4,5
            const v4f W3 = *(const v4f*)(wp + 12);   // codes 6,7
            // one background zero-store per 2 dp: queue depth stays ~2,
            // 128MB of zeros drains under the whole chunk loop
            if ((dp & 1) == 0) {
                const int f = fbase + ((dp >> 1) << 8);
                if (f < (RPB * KCODES - 4) / 4) s4[f] = zf;
            }
            const v2f xr[8] = {X0.xy, X0.zw, X1.xy, X1.zw,
                               X2.xy, X2.zw, X3.xy, X3.zw};
            const v2f wc[8] = {W0.xy, W0.zw, W1.xy, W1.zw,
                               W2.xy, W2.zw, W3.xy, W3.zw};
            #pragma unroll
            for (int r = 0; r < 8; ++r)
                #pragma unroll
                for (int cc = 0; cc < 8; ++cc)
                    acc[r][cc] += xr[r] * wc[cc];    // v_pk_fma_f32 (E,O)
            xp += 256;
            wp += 1024;
        }

        const int kb = c * 128 + kg * 8;             // lane's 8 codes
        const v4f e20 = *(const v4f*)(e2p + kb);
        const v4f e21 = *(const v4f*)(e2p + kb + 4);
        #pragma unroll
        for (int r = 0; r < 8; ++r) {
            const float x2r = (r < 4) ? x2a[r] : x2b[r - 4];
            #pragma unroll
            for (int cc = 0; cc < 8; ++cc) {         // cc ascending: first-min
                const float dot  = acc[r][cc][0] + acc[r][cc][1];   // E + O
                const float e2c  = (cc < 4) ? e20[cc] : e21[cc - 4];
                const float dist = __fsub_rn(__fadd_rn(x2r, e2c),
                                             __fmul_rn(2.0f, dot));
                if (dist < best[r]) { best[r] = dist; bidx[r] = kb + cc; }
            }
        }
    }

    // ---- kg butterfly (16 lanes); explicit lowest-index tie-break
    #pragma unroll
    for (int m = 1; m <= 8; m <<= 1) {
        #pragma unroll
        for (int r = 0; r < 8; ++r) {
            const float ob = __shfl_xor(best[r], m, 64);
            const int   oi = __shfl_xor(bidx[r], m, 64);
            if (ob < best[r] || (ob == best[r] && oi < bidx[r])) {
                best[r] = ob; bidx[r] = oi;
            }
        }
    }
    if (kg == 0) {
        #pragma unroll
        for (int r = 0; r < 8; ++r)
            idxf[rloc + r] = bidx[r];
    }
    __syncthreads();   // idxf visible; vmcnt(0) drain: prefill committed

    // ---- one-hot scatter: ordered after prefill by the barrier's drain
    if (t < RPB)
        slab[(size_t)t * KCODES + idxf[t]] = 1.0f;

    // ---- epilogue: q gather/store + loss; x read from LDS (same values).
    const int rt = t & 127;
    const int dg = t >> 7;            // 2 groups x 32 d (16 dp pairs)
    const int widx = idxf[rt];
    const float* wrow = w + widx * DIM + dg * 32;
    const float* xb = smem + dg * 16 * 256 + (rt >> 3) * 16 + (rt & 7) * 2;
    float* q = out + 1;
    float lsum = 0.0f;
    #pragma unroll
    for (int jj = 0; jj < 16; ++jj) {
        const int dE = dg * 32 + 2 * jj;
        const v2f wp2 = *(const v2f*)(wrow + 2 * jj);     // per-lane, L1-hot
        const v2f xp2 = *(const v2f*)(xb + jj * 256);     // (E,O) from LDS
        const float dfE = __fsub_rn(wp2[0], xp2[0]);      // d ascending: E,O
        lsum = __fadd_rn(lsum, __fmul_rn(dfE, dfE));
        const float dfO = __fsub_rn(wp2[1], xp2[1]);
        lsum = __fadd_rn(lsum, __fmul_rn(dfO, dfO));
        q[(size_t)(b * DIM + dE) * HW + hw0 + rt]     = wp2[0];
        q[(size_t)(b * DIM + dE + 1) * HW + hw0 + rt] = wp2[1];
    }

    #pragma unroll
    for (int off = 32; off; off >>= 1) lsum += __shfl_down(lsum, off, 64);
    if (lane == 0) lred[wv] = lsum;
    __syncthreads();
    if (t == 0)
        partial[blockIdx.x] = (lred[0] + lred[1]) + (lred[2] + lred[3]);
}

__global__ __launch_bounds__(256) void vq_final(
    const float* __restrict__ partial, float* __restrict__ out)
{
    __shared__ float s[256];
    const int t = threadIdx.x;
    s[t] = partial[t] + partial[t + 256];
    __syncthreads();
    for (int off = 128; off; off >>= 1) {
        if (t < off) s[t] += s[t + off];
        __syncthreads();
    }
    if (t == 0) {
        const float m = s[0] / 4194304.0f;            // mean over B*H*W*D
        out[0] = __fadd_rn(m, __fmul_rn(0.25f, m));   // z_q + 0.25*z_e
    }
}

extern "C" void kernel_launch(void* const* d_in, const int* in_sizes, int n_in,
                              void* d_out, int out_size, void* d_ws, size_t ws_size,
                              hipStream_t stream) {
    const float* x = (const float*)d_in[0];
    const float* w = (const float*)d_in[1];
    float* out     = (float*)d_out;
    float* ws      = (float*)d_ws;

    vq_prep<<<2, 256, 0, stream>>>(w, ws);
    vq_main<<<NBLOCKS, TPB, DYN_BYTES, stream>>>(x, w, ws, out, ws + PART_OFF);
    vq_final<<<1, 256, 0, stream>>>(ws + PART_OFF, out);
}

// Round 5
// 226.259 us; speedup vs baseline: 1.3674x; 1.0690x over previous
//
#include <hip/hip_runtime.h>

// VQ-VAE forward: x [64,64,32,32] f32 (NCHW, C==D), weight [512,64] f32.
// d_out: loss (1) | q_out (4194304, NCHW) | encodings (33554432, [N,K]).
//
// R15 = R10 (proven 89.6us: both operands LDS, 4 waves x 128 rows, 4
// code-chunks, register w-prefetch) + encodings-store spreading:
//  - the 128MB one-hot zero-fill moves from the serial per-block tail into
//    the 4 chunk-staging regions (16 v4f stores/thread each), issued next
//    to the existing wstg global loads and drained by the staging barriers
//    that drain vmcnt(0) anyway. The inner dp loop still waits ONLY on
//    lgkmcnt (LDS) -- stores cannot pollute it (R14's failure mode #1).
//  - tail becomes a single 1.0 scatter per row after the argmin barrier
//    (vmcnt(0)-before-s_barrier orders prefill < scatter; same scheme
//    passed correctness in R14).
// Inner loop, staging, dist arithmetic + tie order byte-identical to R10.

#define NROWS 65536
#define DIM 64
#define KCODES 512
#define HW 1024
#define TPB 256
#define RPB 128                     // rows per block
#define NBLOCKS (NROWS / RPB)       // 512

// d_ws float offsets
#define WT_OFF 0                    // wTp [32 dpair][512 k][2] = 32768 floats
#define E2_OFF 32768                // e2 [512]
#define PART_OFF 98816              // partials [512]

// dynamic LDS float offsets
#define XW 8192                     // xs: 32 dp x 128 rows x (E,O)
#define DYN_FLOATS (XW + 32 * 320)  // + w chunk 32 dp x (16 kg x 20) = 18432
#define DYN_BYTES (DYN_FLOATS * 4)  // 73728 B

typedef float v2f __attribute__((ext_vector_type(2)));
typedef float v4f __attribute__((ext_vector_type(4)));

__global__ __launch_bounds__(256) void vq_prep(
    const float* __restrict__ w, float* __restrict__ ws)
{
    // w -> wTp[dpair][k][2] (E,O interleave) + e2 (ascending-d chain)
    const int k = blockIdx.x * 256 + threadIdx.x;
    float s = 0.0f;
    for (int d = 0; d < DIM; ++d) {
        const float v = w[k * DIM + d];
        ws[WT_OFF + (d >> 1) * (KCODES * 2) + k * 2 + (d & 1)] = v;
        s = __fadd_rn(s, __fmul_rn(v, v));
    }
    ws[E2_OFF + k] = s;
}

__global__ __launch_bounds__(TPB) void vq_main(
    const float* __restrict__ x, const float* __restrict__ w,
    const float* __restrict__ ws, float* __restrict__ out,
    float* __restrict__ partial)
{
    extern __shared__ __align__(16) float smem[];   // [0,XW)=xs, [XW..)=wl
    __shared__ int   idxf[RPB];
    __shared__ float x2l[RPB];
    __shared__ float lred[4];

    const int t    = threadIdx.x;
    const int lane = t & 63;
    const int wv   = __builtin_amdgcn_readfirstlane(t >> 6);
    const int rg   = lane >> 4;       // 0..3: rows wv*32 + rg*8 .. +7
    const int kg   = lane & 15;       // 16 groups x 8 codes per chunk
    const int n0   = blockIdx.x * RPB;
    const int b    = n0 >> 10;        // 1024 % 128 == 0: no b straddle
    const int hw0  = n0 & 1023;

    // ---- encodings slab: peel zeros (floats 0..2 and last); shares of
    // 4096 v4f zeros are issued in each staging region below.
    float* slab = out + 1 + (size_t)NROWS * DIM + (size_t)n0 * KCODES;
    v4f* s4 = (v4f*)(slab + 3);                   // 16B-aligned
    const v4f zf = (v4f){0.0f, 0.0f, 0.0f, 0.0f};
    if (t < 3) slab[t] = 0.0f;
    if (t == 4) slab[RPB * KCODES - 1] = 0.0f;

    // ---- prefetch w chunk 0 into staging regs (independent of xs staging)
    v4f wstg[8];
    {
        const float* src = ws + WT_OFF;
        #pragma unroll
        for (int i = 0; i < 8; ++i) {
            const int s = i * 1024 + t * 4;
            wstg[i] = *(const v4f*)(src + (s >> 8) * 1024 + (s & 255));
        }
    }

    // ---- stage x tile (128 rows) into LDS, (E,O) interleaved, unpadded:
    // xs[dp*256 + (row>>3)*16 + (row&7)*2 (+1 for odd d)]
    #pragma unroll
    for (int i = 0; i < 4; ++i) {
        const int task = i * 256 + t;          // 1024 tasks
        const int dp   = task >> 5;
        const int row4 = (task & 31) * 4;
        const float* pe = x + (size_t)(b * DIM + 2 * dp) * HW + hw0 + row4;
        const v4f xe = *(const v4f*)pe;        // 4 rows, even depth
        const v4f xo = *(const v4f*)(pe + HW); // 4 rows, odd depth
        float* dst = smem + dp * 256 + (row4 >> 3) * 16 + (row4 & 7) * 2;
        *(v4f*)dst       = (v4f){xe.x, xo.x, xe.y, xo.y};
        *(v4f*)(dst + 4) = (v4f){xe.z, xo.z, xe.w, xo.w};
    }

    // ---- share 0 of the zero-prefill (f in [0,4096)): drains at the
    // first barrier together with the x/w staging loads.
    #pragma unroll
    for (int k2 = 0; k2 < 16; ++k2)
        s4[t + k2 * 256] = zf;

    __syncthreads();   // xs visible (+ share-0 zeros committed)

    // ---- x2 per row from LDS: same ascending-d mul-then-add chain as prep's
    if (t < RPB) {
        const float* xb = smem + (t >> 3) * 16 + (t & 7) * 2;
        float s = 0.0f;
        #pragma unroll 8
        for (int dp = 0; dp < 32; ++dp) {
            const v2f p = *(const v2f*)(xb + dp * 256);   // (E,O) of d=2dp
            s = __fadd_rn(s, __fmul_rn(p[0], p[0]));
            s = __fadd_rn(s, __fmul_rn(p[1], p[1]));
        }
        x2l[t] = s;
    }

    // ---- write w chunk 0 to LDS; prefetch chunk 1
    #pragma unroll
    for (int i = 0; i < 8; ++i) {
        const int s   = i * 1024 + t * 4;
        const int dp  = s >> 8;
        const int lc0 = (s & 255) >> 1;
        *(v4f*)(smem + XW + dp * 320 + (lc0 >> 3) * 20 + (lc0 & 7) * 2)
            = wstg[i];
    }
    {
        const float* src = ws + WT_OFF + 256;
        #pragma unroll
        for (int i = 0; i < 8; ++i) {
            const int s = i * 1024 + t * 4;
            wstg[i] = *(const v4f*)(src + (s >> 8) * 1024 + (s & 255));
        }
    }
    __syncthreads();   // x2l + w chunk 0 visible

    const float* e2p = ws + E2_OFF;
    const int cj = wv * 4 + rg;                // x row-chunk id (0..15)
    const int rloc = wv * 32 + rg * 8;         // first row (block-local)
    const v4f x2a = *(const v4f*)(x2l + rloc);
    const v4f x2b = *(const v4f*)(x2l + rloc + 4);

    float best[8];
    int   bidx[8];
    #pragma unroll
    for (int r = 0; r < 8; ++r) { best[r] = 3.4e38f; bidx[r] = 0; }

    // ---- 4 chunks of 128 codes, ascending (=> per-lane k ascending)
    #pragma unroll 1
    for (int c = 0; c < 4; ++c) {
        v2f acc[8][8];
        #pragma unroll
        for (int r = 0; r < 8; ++r)
            #pragma unroll
            for (int cc = 0; cc < 8; ++cc) acc[r][cc] = (v2f){0.f, 0.f};

        const float* xp = smem + cj * 16;
        const float* wp = smem + XW + kg * 20;
        #pragma unroll 4
        for (int dp = 0; dp < 32; ++dp) {
            const v4f X0 = *(const v4f*)(xp);        // rows 0,1 (E,O) pairs
            const v4f X1 = *(const v4f*)(xp + 4);    // rows 2,3
            const v4f X2 = *(const v4f*)(xp + 8);    // rows 4,5
            const v4f X3 = *(const v4f*)(xp + 12);   // rows 6,7
            const v4f W0 = *(const v4f*)(wp);        // codes 0,1 (E,O) pairs
            const v4f W1 = *(const v4f*)(wp + 4);    // codes 2,3
            const v4f W2 = *(const v4f*)(wp + 8);    // codes 4,5
            const v4f W3 = *(const v4f*)(wp + 12);   // codes 6,7
            const v2f xr[8] = {X0.xy, X0.zw, X1.xy, X1.zw,
                               X2.xy, X2.zw, X3.xy, X3.zw};
            const v2f wc[8] = {W0.xy, W0.zw, W1.xy, W1.zw,
                               W2.xy, W2.zw, W3.xy, W3.zw};
            #pragma unroll
            for (int r = 0; r < 8; ++r)
                #pragma unroll
                for (int cc = 0; cc < 8; ++cc)
                    acc[r][cc] += xr[r] * wc[cc];    // v_pk_fma_f32 (E,O)
            xp += 256;
            wp += 320;
        }

        const int kb = c * 128 + kg * 8;             // lane's 8 codes
        const v4f e20 = *(const v4f*)(e2p + kb);
        const v4f e21 = *(const v4f*)(e2p + kb + 4);
        #pragma unroll
        for (int r = 0; r < 8; ++r) {
            const float x2r = (r < 4) ? x2a[r] : x2b[r - 4];
            #pragma unroll
            for (int cc = 0; cc < 8; ++cc) {         // cc ascending: first-min
                const float dot  = acc[r][cc][0] + acc[r][cc][1];   // E + O
                const float e2c  = (cc < 4) ? e20[cc] : e21[cc - 4];
                const float dist = __fsub_rn(__fadd_rn(x2r, e2c),
                                             __fmul_rn(2.0f, dot));
                if (dist < best[r]) { best[r] = dist; bidx[r] = kb + cc; }
            }
        }

        if (c < 3) {
            __syncthreads();   // all reads of w chunk c done
            // share c+1 of the zero-prefill (f in [(c+1)*4096,(c+2)*4096)):
            // issued here, drained by the closing staging barrier (which
            // drains vmcnt(0) for the wstg prefetch loads anyway). The dp
            // loop above never waits vmcnt -> no pollution.
            {
                const int f0 = (c + 1) * 4096 + t;
                #pragma unroll
                for (int k2 = 0; k2 < 16; ++k2) {
                    const int f = f0 + k2 * 256;
                    if (f < 16383) s4[f] = zf;       // nf4 = 16383
                }
            }
            #pragma unroll
            for (int i = 0; i < 8; ++i) {            // write chunk c+1
                const int s   = i * 1024 + t * 4;
                const int dp  = s >> 8;
                const int lc0 = (s & 255) >> 1;
                *(v4f*)(smem + XW + dp * 320 + (lc0 >> 3) * 20
                        + (lc0 & 7) * 2) = wstg[i];
            }
            if (c < 2) {                             // prefetch chunk c+2
                const float* src = ws + WT_OFF + (c + 2) * 256;
                #pragma unroll
                for (int i = 0; i < 8; ++i) {
                    const int s = i * 1024 + t * 4;
                    wstg[i] = *(const v4f*)(src + (s >> 8) * 1024 + (s & 255));
                }
            }
            __syncthreads();   // chunk c+1 visible (+ share zeros committed)
        }
    }

    // ---- kg butterfly (16 lanes); explicit lowest-index tie-break
    #pragma unroll
    for (int m = 1; m <= 8; m <<= 1) {
        #pragma unroll
        for (int r = 0; r < 8; ++r) {
            const float ob = __shfl_xor(best[r], m, 64);
            const int   oi = __shfl_xor(bidx[r], m, 64);
            if (ob < best[r] || (ob == best[r] && oi < bidx[r])) {
                best[r] = ob; bidx[r] = oi;
            }
        }
    }
    if (kg == 0) {
        #pragma unroll
        for (int r = 0; r < 8; ++r)
            idxf[rloc + r] = bidx[r];
    }
    __syncthreads();   // idxf visible; vmcnt(0) drain: ALL prefill committed

    // ---- one-hot scatter: ordered after prefill by the barrier's drain
    if (t < RPB)
        slab[(size_t)t * KCODES + idxf[t]] = 1.0f;

    // ---- epilogue: q gather/store + loss; x read from LDS (same values).
    const int rt = t & 127;
    const int dg = t >> 7;            // 2 groups x 32 d (16 dp pairs)
    const int widx = idxf[rt];
    const float* wrow = w + widx * DIM + dg * 32;
    const float* xb = smem + dg * 16 * 256 + (rt >> 3) * 16 + (rt & 7) * 2;
    float* q = out + 1;
    float lsum = 0.0f;
    #pragma unroll
    for (int jj = 0; jj < 16; ++jj) {
        const int dE = dg * 32 + 2 * jj;
        const v2f wp2 = *(const v2f*)(wrow + 2 * jj);     // per-lane, L1-hot
        const v2f xp2 = *(const v2f*)(xb + jj * 256);     // (E,O) from LDS
        const float dfE = __fsub_rn(wp2[0], xp2[0]);      // d ascending: E,O
        lsum = __fadd_rn(lsum, __fmul_rn(dfE, dfE));
        const float dfO = __fsub_rn(wp2[1], xp2[1]);
        lsum = __fadd_rn(lsum, __fmul_rn(dfO, dfO));
        q[(size_t)(b * DIM + dE) * HW + hw0 + rt]     = wp2[0];
        q[(size_t)(b * DIM + dE + 1) * HW + hw0 + rt] = wp2[1];
    }

    #pragma unroll
    for (int off = 32; off; off >>= 1) lsum += __shfl_down(lsum, off, 64);
    if (lane == 0) lred[wv] = lsum;
    __syncthreads();
    if (t == 0)
        partial[blockIdx.x] = (lred[0] + lred[1]) + (lred[2] + lred[3]);
}

__global__ __launch_bounds__(256) void vq_final(
    const float* __restrict__ partial, float* __restrict__ out)
{
    __shared__ float s[256];
    const int t = threadIdx.x;
    s[t] = partial[t] + partial[t + 256];
    __syncthreads();
    for (int off = 128; off; off >>= 1) {
        if (t < off) s[t] += s[t + off];
        __syncthreads();
    }
    if (t == 0) {
        const float m = s[0] / 4194304.0f;            // mean over B*H*W*D
        out[0] = __fadd_rn(m, __fmul_rn(0.25f, m));   // z_q + 0.25*z_e
    }
}

extern "C" void kernel_launch(void* const* d_in, const int* in_sizes, int n_in,
                              void* d_out, int out_size, void* d_ws, size_t ws_size,
                              hipStream_t stream) {
    const float* x = (const float*)d_in[0];
    const float* w = (const float*)d_in[1];
    float* out     = (float*)d_out;
    float* ws      = (float*)d_ws;

    // 73728 B dynamic LDS > 64 KB default limit: opt in (host-side,
    // idempotent, graph-capture-safe — not a stream op).
    (void)hipFuncSetAttribute((const void*)vq_main,
                              hipFuncAttributeMaxDynamicSharedMemorySize,
                              DYN_BYTES);

    vq_prep<<<2, 256, 0, stream>>>(w, ws);
    vq_main<<<NBLOCKS, TPB, DYN_BYTES, stream>>>(x, w, ws, out, ws + PART_OFF);
    vq_final<<<1, 256, 0, stream>>>(ws + PART_OFF, out);
}